// Round 1
// baseline (260.700 us; speedup 1.0000x reference)
//
#include <hip/hip_runtime.h>
#include <stdint.h>

// ClusteringLayer: q = rownorm(1/(1 + ||x||^2 + ||c||^2 - 2 x@c^T))
// N=65536, D=512, K=512. Strategy: bf16 MFMA GEMM fused with Student-t +
// row normalization (full K per block so no second pass over the 134MB output).

#define D 512
#define K 512
#define BM 64
#define BK 64          // D-chunk per LDS stage
#define NCHUNK (D / BK)
#define THREADS 512

typedef __attribute__((ext_vector_type(8))) short short8;   // 8 x bf16 (4 VGPRs)
typedef __attribute__((ext_vector_type(4))) float floatx4;  // MFMA acc

// fp32 -> bf16 round-to-nearest-even
__device__ __forceinline__ uint16_t f2bf(float f) {
  uint32_t u = __float_as_uint(f);
  u += 0x7FFFu + ((u >> 16) & 1u);
  return (uint16_t)(u >> 16);
}

// ---------------------------------------------------------------------------
// Prep: centroids fp32 -> bf16 in a pre-swizzled "LDS image" layout so the
// main kernel can DMA it with global_load_lds (wave-uniform base + lane*16),
// plus ||c||^2 per centroid.
// Layout: chunk c (of D/64), row r (0..511), group g (8 bf16 = 16B):
//   slot = (c*K + r)*8 + (g ^ (r & 7))   -> 16B each, stored contiguously.
// The XOR swizzle spreads the 8 groups of a row across banks so that MFMA
// fragment reads (16 lanes hitting 16 different rows at the same group) are
// conflict-free (2-way max = free per m136).
// ---------------------------------------------------------------------------
__global__ __launch_bounds__(64)
void prep_kernel(const float* __restrict__ cent, float* __restrict__ csq,
                 uint16_t* __restrict__ bbf) {
  const int row  = blockIdx.x;     // 0..511
  const int lane = threadIdx.x;    // 0..63, covers 8 floats each
  const float4* src = (const float4*)(cent + (size_t)row * D + lane * 8);
  float4 v0 = src[0];
  float4 v1 = src[1];
  float ss = v0.x*v0.x + v0.y*v0.y + v0.z*v0.z + v0.w*v0.w
           + v1.x*v1.x + v1.y*v1.y + v1.z*v1.z + v1.w*v1.w;
  uint4 pk;
  pk.x = (uint32_t)f2bf(v0.x) | ((uint32_t)f2bf(v0.y) << 16);
  pk.y = (uint32_t)f2bf(v0.z) | ((uint32_t)f2bf(v0.w) << 16);
  pk.z = (uint32_t)f2bf(v1.x) | ((uint32_t)f2bf(v1.y) << 16);
  pk.w = (uint32_t)f2bf(v1.z) | ((uint32_t)f2bf(v1.w) << 16);
  const int c = lane >> 3;         // chunk
  const int g = lane & 7;          // group within chunk
  const int slot = (c * K + row) * 8 + (g ^ (row & 7));
  *(uint4*)(bbf + (size_t)slot * 8) = pk;
  #pragma unroll
  for (int m = 1; m < 64; m <<= 1) ss += __shfl_xor(ss, m);
  if (lane == 0) csq[row] = ss;
}

// ---------------------------------------------------------------------------
// Main fused kernel. Block = 64 rows x all 512 centroids.
// 8 waves; wave w owns cols [64w, 64w+64): 4x4 grid of 16x16x32 bf16 MFMA.
// ---------------------------------------------------------------------------
__global__ __launch_bounds__(THREADS, 4)
void cluster_main(const float* __restrict__ x, const uint16_t* __restrict__ bbf,
                  const float* __restrict__ csq, float* __restrict__ out) {
  __shared__ __align__(16) uint16_t lA[BM * BK];     // 8 KB, swizzled
  __shared__ __align__(16) uint16_t lB[K * BK];      // 64 KB, swizzled DMA image
  __shared__ float lcsq[K];                          // 2 KB
  __shared__ float lxsq[BM];
  __shared__ float lrow[BM];

  const int tid  = threadIdx.x;
  const int wave = tid >> 6;
  const int lane = tid & 63;
  const int p    = lane & 15;     // MFMA row/col-within-16
  const int quad = lane >> 4;     // MFMA quad
  const int row0 = blockIdx.x * BM;

  lcsq[tid] = csq[tid];
  if (tid < BM) { lxsq[tid] = 0.f; lrow[tid] = 0.f; }

  // A staging assignment (chunk-invariant): thread -> (row ar, 8-col group ag)
  const int ar = tid >> 3;        // 0..63
  const int ag = tid & 7;
  const float* aptr = x + (size_t)(row0 + ar) * D + ag * 8;
  uint16_t* adst = &lA[(size_t)(ar * 8 + (ag ^ (ar & 7))) * 8];
  float xacc = 0.f;               // partial ||x||^2 for row ar

  floatx4 acc[4][4];
  #pragma unroll
  for (int mi = 0; mi < 4; ++mi)
    #pragma unroll
    for (int ni = 0; ni < 4; ++ni)
      acc[mi][ni] = (floatx4){0.f, 0.f, 0.f, 0.f};

  for (int c = 0; c < NCHUNK; ++c) {
    __syncthreads();  // prev compute done (and, at c=0, LDS inits visible)

    // --- stage A: 64x64 fp32 -> bf16, accumulate x^2 on the way ---
    float4 v0 = *(const float4*)(aptr);
    float4 v1 = *(const float4*)(aptr + 4);
    aptr += BK;
    xacc += v0.x*v0.x + v0.y*v0.y + v0.z*v0.z + v0.w*v0.w
          + v1.x*v1.x + v1.y*v1.y + v1.z*v1.z + v1.w*v1.w;
    uint4 pk;
    pk.x = (uint32_t)f2bf(v0.x) | ((uint32_t)f2bf(v0.y) << 16);
    pk.y = (uint32_t)f2bf(v0.z) | ((uint32_t)f2bf(v0.w) << 16);
    pk.z = (uint32_t)f2bf(v1.x) | ((uint32_t)f2bf(v1.y) << 16);
    pk.w = (uint32_t)f2bf(v1.z) | ((uint32_t)f2bf(v1.w) << 16);
    *(uint4*)adst = pk;

    // --- stage B: flat 64KB DMA of the pre-swizzled chunk image ---
    {
      const uint16_t* bsrc = bbf + (size_t)c * (K * BK) + wave * 4096 + lane * 8;
      #pragma unroll
      for (int j = 0; j < 8; ++j) {
        __builtin_amdgcn_global_load_lds(
            (const __attribute__((address_space(1))) uint32_t*)(bsrc + j * 512),
            (__attribute__((address_space(3))) uint32_t*)(&lB[wave * 4096 + j * 512]),
            16, 0, 0);
      }
    }

    __syncthreads();

    // --- compute: 2 k-steps of 32, 16 MFMAs each ---
    #pragma unroll
    for (int kk = 0; kk < 2; ++kk) {
      short8 af[4], bfr[4];
      #pragma unroll
      for (int mi = 0; mi < 4; ++mi) {
        const int r = mi * 16 + p;
        const int g = (kk * 4 + quad) ^ (r & 7);
        af[mi] = *(const short8*)&lA[(size_t)(r * 8 + g) * 8];
      }
      #pragma unroll
      for (int ni = 0; ni < 4; ++ni) {
        const int r = wave * 64 + ni * 16 + p;
        const int g = (kk * 4 + quad) ^ (r & 7);
        bfr[ni] = *(const short8*)&lB[(size_t)(r * 8 + g) * 8];
      }
      #pragma unroll
      for (int mi = 0; mi < 4; ++mi)
        #pragma unroll
        for (int ni = 0; ni < 4; ++ni)
          acc[mi][ni] = __builtin_amdgcn_mfma_f32_16x16x32_bf16(
              af[mi], bfr[ni], acc[mi][ni], 0, 0, 0);
    }
  }

  // ||x||^2 per row (8 partial contributors per row)
  atomicAdd(&lxsq[ar], xacc);
  __syncthreads();

  // --- epilogue: q = rcp(1 + xsq + csq - 2*dot); fused row-normalize ---
  float xs[4][4];   // [mi][rr]
  #pragma unroll
  for (int mi = 0; mi < 4; ++mi)
    #pragma unroll
    for (int rr = 0; rr < 4; ++rr)
      xs[mi][rr] = lxsq[mi * 16 + quad * 4 + rr];
  float cs[4];
  #pragma unroll
  for (int ni = 0; ni < 4; ++ni)
    cs[ni] = lcsq[wave * 64 + ni * 16 + p];

  float rp[4][4];
  #pragma unroll
  for (int mi = 0; mi < 4; ++mi)
    #pragma unroll
    for (int rr = 0; rr < 4; ++rr)
      rp[mi][rr] = 0.f;

  #pragma unroll
  for (int mi = 0; mi < 4; ++mi)
    #pragma unroll
    for (int ni = 0; ni < 4; ++ni)
      #pragma unroll
      for (int rr = 0; rr < 4; ++rr) {
        const float d = 1.0f + xs[mi][rr] + cs[ni] - 2.0f * acc[mi][ni][rr];
        const float q = __builtin_amdgcn_rcpf(d);  // d ~ 1000, 1ulp is plenty
        acc[mi][ni][rr] = q;
        rp[mi][rr] += q;
      }

  // reduce row partials across the 16 lanes sharing a quad, then LDS-atomic
  #pragma unroll
  for (int mi = 0; mi < 4; ++mi)
    #pragma unroll
    for (int rr = 0; rr < 4; ++rr) {
      float v = rp[mi][rr];
      v += __shfl_xor(v, 1);
      v += __shfl_xor(v, 2);
      v += __shfl_xor(v, 4);
      v += __shfl_xor(v, 8);
      if (p == 0) atomicAdd(&lrow[mi * 16 + quad * 4 + rr], v);
    }
  __syncthreads();

  #pragma unroll
  for (int mi = 0; mi < 4; ++mi) {
    #pragma unroll
    for (int rr = 0; rr < 4; ++rr) {
      const int row = mi * 16 + quad * 4 + rr;
      const float inv = __builtin_amdgcn_rcpf(lrow[row]);
      float* orow = out + (size_t)(row0 + row) * K + wave * 64 + p;
      #pragma unroll
      for (int ni = 0; ni < 4; ++ni)
        orow[ni * 16] = acc[mi][ni][rr] * inv;
    }
  }
}

extern "C" void kernel_launch(void* const* d_in, const int* in_sizes, int n_in,
                              void* d_out, int out_size, void* d_ws, size_t ws_size,
                              hipStream_t stream) {
  const float* x    = (const float*)d_in[0];
  const float* cent = (const float*)d_in[1];
  float* out = (float*)d_out;

  // ws layout: csq[512] floats (2KB) | bbf bf16 image (512KB). Needs 526KB.
  float*    csq = (float*)d_ws;
  uint16_t* bbf = (uint16_t*)((char*)d_ws + 2048);

  const int N = in_sizes[0] / D;      // 65536
  prep_kernel<<<K, 64, 0, stream>>>(cent, csq, bbf);
  cluster_main<<<N / BM, THREADS, 0, stream>>>(x, bbf, csq, out);
}